// Round 18
// baseline (40.190 us; speedup 1.0000x reference)
//
#include <hip/hip_runtime.h>
#include <hip/hip_fp16.h>
#include <math.h>

#define IMG_H 512
#define IMG_W 512
#define CH    3
#define TILE_W 16
#define TILE_H 128               // eight 16-row eighths (A..H)
#define QTR   16
#define NQ    8
#define PAD   2
#define TP    20                 // padded per-eighth tile: 20 rows x 20 cols

#if __has_builtin(__builtin_amdgcn_rcpf)
#define RCP(x) __builtin_amdgcn_rcpf(x)
#else
#define RCP(x) (1.0f / (x))
#endif

__device__ __forceinline__ int reflect_idx(int i, int n) {
    i = (i < 0) ? -i : i;
    i = (i >= n) ? (2 * n - 2 - i) : i;
    return i;
}

__device__ __forceinline__ __half2 bch(unsigned int u) {
    return __builtin_bit_cast(__half2, u);
}
__device__ __forceinline__ unsigned int hcb(__half2 h) {
    return __builtin_bit_cast(unsigned int, h);
}

__global__ __launch_bounds__(256)
void bilateral_kernel(const float* __restrict__ in, float* __restrict__ out) {
    // 8 px/thread: same column, rows r + 16q (q=0..7), channel-PLANAR quads:
    //   HX[r][c] = (x_AB, x_CD, x_EF, x_GH)  (uint4 of half2 -> ds_read_b128)
    //   HY, HZ likewise. 3 b128 per tap serve 8 px (4.7 B/px/tap).
    // Same R15 math (f16 direct-difference, absmax 0.0039 proven), same
    // stride-20 + rp-permutation LDS geometry (measured 0 conflicts in
    // R3/R6/R12/R15/R17). Fully-unrolled tap loop = the shape the compiler
    // provably does NOT hoist (R15: 28 VGPR).
    __shared__ uint4 HX[TP][TP];   // 6.4 KB
    __shared__ uint4 HY[TP][TP];   // 6.4 KB
    __shared__ uint4 HZ[TP][TP];   // 6.4 KB   (19.2 KB total -> 8 blocks/CU)

    const int b  = blockIdx.z;
    const int by = blockIdx.y * TILE_H;
    const int bx = blockIdx.x * TILE_W;
    const int tx = threadIdx.x;
    const int ty = threadIdx.y;
    const int tid = ty * TILE_W + tx;

    // Staging: 400 entries, each covers 8 pixels (eighths A..H).
    for (int i = tid; i < TP * TP; i += 256) {
        const int r  = i / TP;
        const int cc = i - r * TP;
        const int gx = reflect_idx(bx + cc - PAD, IMG_W);
        float xs[NQ], ys[NQ], zs[NQ];
        #pragma unroll
        for (int q = 0; q < NQ; ++q) {
            const int gy = reflect_idx(by + q * QTR + r - PAD, IMG_H);
            const float* p = in + ((size_t)(b * IMG_H + gy) * IMG_W + gx) * CH;
            xs[q] = p[0]; ys[q] = p[1]; zs[q] = p[2];
        }
        uint4 hx, hy, hz;
        hx.x = hcb(__floats2half2_rn(xs[0], xs[1]));
        hx.y = hcb(__floats2half2_rn(xs[2], xs[3]));
        hx.z = hcb(__floats2half2_rn(xs[4], xs[5]));
        hx.w = hcb(__floats2half2_rn(xs[6], xs[7]));
        hy.x = hcb(__floats2half2_rn(ys[0], ys[1]));
        hy.y = hcb(__floats2half2_rn(ys[2], ys[3]));
        hy.z = hcb(__floats2half2_rn(ys[4], ys[5]));
        hy.w = hcb(__floats2half2_rn(ys[6], ys[7]));
        hz.x = hcb(__floats2half2_rn(zs[0], zs[1]));
        hz.y = hcb(__floats2half2_rn(zs[2], zs[3]));
        hz.z = hcb(__floats2half2_rn(zs[4], zs[5]));
        hz.w = hcb(__floats2half2_rn(zs[6], zs[7]));
        HX[r][cc] = hx; HY[r][cc] = hy; HZ[r][cc] = hz;
    }
    __syncthreads();

    // Row permutation: ty 0..3 -> rows 0,4,8,12 within each wave (conflict-free).
    const int rp = ((ty & 3) << 2) | (ty >> 2);

    // arg = K2*d2 + log2(spatial); K2 = -log2(e)/(2*0.04^2).
    const __half2 K2 = __float2half2_rn(-450.8422f);
    const __half2 B2[3][3] = {
        { __float2half2_rn(-8.395800f), __float2half2_rn(-6.231757f), __float2half2_rn(-5.510409f) },
        { __float2half2_rn(-6.231757f), __float2half2_rn(-4.067714f), __float2half2_rn(-3.346367f) },
        { __float2half2_rn(-5.510409f), __float2half2_rn(-3.346367f), __float2half2_rn(-2.625024f) },
    };

    const uint4 cX = HX[rp + PAD][tx + PAD];
    const uint4 cY = HY[rp + PAD][tx + PAD];
    const uint4 cZ = HZ[rp + PAD][tx + PAD];

    const __half2 z2 = __float2half2_rn(0.0f);
    // Accumulators per stream s in {AB,CD,EF,GH} = components {x,y,z,w}.
    __half2 nx0 = z2, ny0 = z2, nz0 = z2, nd0 = z2;
    __half2 nx1 = z2, ny1 = z2, nz1 = z2, nd1 = z2;
    __half2 nx2 = z2, ny2 = z2, nz2 = z2, nd2 = z2;
    __half2 nx3 = z2, ny3 = z2, nz3 = z2, nd3 = z2;

#define STREAM(comp, cXc, cYc, cZc, nx, ny, nz, nd)                          \
    {                                                                        \
        const __half2 sx = bch(P.comp), sy = bch(Y.comp), sz = bch(Z.comp);  \
        const __half2 dx = __hsub2(sx, bch(cXc));                            \
        const __half2 dh = __hsub2(sy, bch(cYc));                            \
        const __half2 dz = __hsub2(sz, bch(cZc));                            \
        const __half2 d2 = __hfma2(dx, dx, __hfma2(dh, dh, __hmul2(dz, dz))); \
        const __half2 w = h2exp2(__hfma2(d2, K2, Bv));                       \
        nx = __hfma2(w, sx, nx);                                             \
        ny = __hfma2(w, sy, ny);                                             \
        nz = __hfma2(w, sz, nz);                                             \
        nd = __hadd2(nd, w);                                                 \
    }

    #pragma unroll
    for (int dy = 0; dy < 5; ++dy) {
        const int iy = (dy < 3) ? dy : 4 - dy;
        #pragma unroll
        for (int k = 0; k < 5; ++k) {
            const int ix = (k < 3) ? k : 4 - k;
            const uint4 P = HX[rp + dy][tx + k];
            const uint4 Y = HY[rp + dy][tx + k];
            const uint4 Z = HZ[rp + dy][tx + k];
            const __half2 Bv = B2[iy][ix];
            STREAM(x, cX.x, cY.x, cZ.x, nx0, ny0, nz0, nd0)
            STREAM(y, cX.y, cY.y, cZ.y, nx1, ny1, nz1, nd1)
            STREAM(z, cX.z, cY.z, cZ.z, nx2, ny2, nz2, nd2)
            STREAM(w, cX.w, cY.w, cZ.w, nx3, ny3, nz3, nd3)
        }
    }
#undef STREAM

    const int xcol = bx + tx;
#define EMIT(q, nx, ny, nz, nd, SEL_LO)                                      \
    {                                                                        \
        const float n0 = SEL_LO ? __low2float(nx) : __high2float(nx);        \
        const float n1 = SEL_LO ? __low2float(ny) : __high2float(ny);        \
        const float n2 = SEL_LO ? __low2float(nz) : __high2float(nz);        \
        const float dn = SEL_LO ? __low2float(nd) : __high2float(nd);        \
        const float inv = RCP(dn);                                           \
        const int y = by + (q) * QTR + rp;                                   \
        float* dst = out + ((size_t)(b * IMG_H + y) * IMG_W + xcol) * CH;    \
        dst[0] = fminf(fmaxf(n0 * inv, 0.0f), 1.0f);                         \
        dst[1] = fminf(fmaxf(n1 * inv, 0.0f), 1.0f);                         \
        dst[2] = fminf(fmaxf(n2 * inv, 0.0f), 1.0f);                         \
    }
    EMIT(0, nx0, ny0, nz0, nd0, 1)
    EMIT(1, nx0, ny0, nz0, nd0, 0)
    EMIT(2, nx1, ny1, nz1, nd1, 1)
    EMIT(3, nx1, ny1, nz1, nd1, 0)
    EMIT(4, nx2, ny2, nz2, nd2, 1)
    EMIT(5, nx2, ny2, nz2, nd2, 0)
    EMIT(6, nx3, ny3, nz3, nd3, 1)
    EMIT(7, nx3, ny3, nz3, nd3, 0)
#undef EMIT
}

extern "C" void kernel_launch(void* const* d_in, const int* in_sizes, int n_in,
                              void* d_out, int out_size, void* d_ws, size_t ws_size,
                              hipStream_t stream) {
    const float* in = (const float*)d_in[0];
    float* out = (float*)d_out;
    const int B = in_sizes[0] / (IMG_H * IMG_W * CH);   // 16

    dim3 block(TILE_W, 16, 1);
    dim3 grid(IMG_W / TILE_W, IMG_H / TILE_H, B);       // 32 x 4 x 16
    bilateral_kernel<<<grid, block, 0, stream>>>(in, out);
}